// Round 2
// 215.764 us; speedup vs baseline: 1.0202x; 1.0202x over previous
//
#include <hip/hip_runtime.h>

// LaneAttention: per-lane MLP score -> per-group(8) softmax -> weighted pool of
// concat(ht, info, future) into out[32768, 192] fp32.
//
// R4 == R3 resubmitted (R3 bench died in container infra, no kernel signal).
// R2 was latency-bound (VALUBusy 10%, hbm 29%, occupancy 37%): single-wave
// 64-thread blocks hit the 16-workgroups/CU cap -> only 16 waves/CU resident,
// and each wave's full 128-dim MLP + 8-group pooling path was latency-exposed.
// Now: 128-thread (2-wave) blocks, same 64 rows per block. Wave 0 accumulates
// the ht-half of W1, wave 1 the info-half (W1 offset is wave-uniform ->
// weights stay SGPR/scalar operands). Partial h[16] combined through a
// 17-padded LDS buffer (conflict-free), then each wave scores + softmaxes +
// pools its own 32 rows (4 groups). 16 blocks/CU x 2 waves = 32 waves/CU
// (2x latency hiding), per-wave critical path halved.

__global__ __launch_bounds__(128, 8) void lane_attn_kernel(
    const float* __restrict__ ht,     // [M,64]
    const float* __restrict__ info,   // [M,64]
    const float* __restrict__ fut,    // [M,64]
    const float* __restrict__ W1,     // [128,16]
    const float* __restrict__ b1,     // [16]
    const float* __restrict__ W2,     // [16]
    const float* __restrict__ b2,     // [1]
    const int*   __restrict__ seg,    // [M]
    float*       __restrict__ out)    // [N_GROUPS,192]
{
    const int t    = threadIdx.x & 63;                                  // lane
    const int w    = __builtin_amdgcn_readfirstlane(threadIdx.x >> 6);  // wave 0/1 (SGPR)
    const int base = blockIdx.x * 64;                                   // block's first row

    // [wave][row][16 padded to 17] -- 17 is odd => bank = (row*17+j)%32 is a
    // bijection in row over any 32 consecutive rows => conflict-free r/w.
    __shared__ float hpart[2][64][17];

    // ---------------- phase 1: half-MLP partial per wave ----------------
    // Wave w covers input dims [w*64, w*64+64) of ALL 64 rows of the block.
    // W1 row offset is wave-uniform -> scalar loads feed v_fma as SGPR operands.
    float h[16];
#pragma unroll
    for (int j = 0; j < 16; ++j) h[j] = w ? 0.0f : b1[j];  // add b1 exactly once

    const float*  src = w ? info : ht;
    const float*  w1  = W1 + w * (64 * 16);
    const float4* p   = (const float4*)(src + (size_t)(base + t) * 64);

#pragma unroll 8
    for (int k4 = 0; k4 < 16; ++k4) {
        float4 v = p[k4];
#pragma unroll
        for (int j = 0; j < 16; ++j) {
            h[j] = fmaf(v.x, w1[(k4 * 4 + 0) * 16 + j], h[j]);
            h[j] = fmaf(v.y, w1[(k4 * 4 + 1) * 16 + j], h[j]);
            h[j] = fmaf(v.z, w1[(k4 * 4 + 2) * 16 + j], h[j]);
            h[j] = fmaf(v.w, w1[(k4 * 4 + 3) * 16 + j], h[j]);
        }
    }

#pragma unroll
    for (int j = 0; j < 16; ++j) hpart[w][t][j] = h[j];
    __syncthreads();

    // ------------- score + softmax: each wave owns 32 rows -------------
    // Local row lr = w*32 + (t&31); lanes t and t+32 duplicate the same row
    // (broadcast LDS reads), so shfl sources 0..31 below are always valid.
    const int lr = w * 32 + (t & 31);
    float score = b2[0];
#pragma unroll
    for (int j = 0; j < 16; ++j) {
        const float hj = hpart[0][lr][j] + hpart[1][lr][j];
        score = fmaf(fmaxf(hj, 0.0f), W2[j], score);
    }

    float m = score;
    m = fmaxf(m, __shfl_xor(m, 1));
    m = fmaxf(m, __shfl_xor(m, 2));
    m = fmaxf(m, __shfl_xor(m, 4));
    float e = __expf(score - m);
    float s = e;
    s += __shfl_xor(s, 1);
    s += __shfl_xor(s, 2);
    s += __shfl_xor(s, 4);
    const float prob = e / s;   // lane t holds prob of row base + w*32 + (t&31)

    // ---------------- phase 2: pooling, 4 groups per wave ----------------
    // Thread c covers column c of each array; row reads are coalesced 256B.
    // ht (wave 0) / info (wave 1) rows are L1/L2-hot from phase 1.
    const int c = t;
    for (int gg = 0; gg < 4; ++gg) {
        const int r0  = base + w * 32 + gg * 8;
        const int gid = seg[r0];          // wave-uniform -> scalar load
        float a0 = 0.0f, a1 = 0.0f, a2 = 0.0f;
#pragma unroll
        for (int i = 0; i < 8; ++i) {
            const float  pb = __shfl(prob, gg * 8 + i);
            const size_t r  = (size_t)(r0 + i) * 64;
            a0 = fmaf(pb, ht[r + c],   a0);
            a1 = fmaf(pb, info[r + c], a1);
            a2 = fmaf(pb, fut[r + c],  a2);
        }
        float* o = out + (size_t)gid * 192;
        o[c]       = a0;
        o[64 + c]  = a1;
        o[128 + c] = a2;
    }
}

extern "C" void kernel_launch(void* const* d_in, const int* in_sizes, int n_in,
                              void* d_out, int out_size, void* d_ws, size_t ws_size,
                              hipStream_t stream) {
    const float* ht   = (const float*)d_in[0];
    const float* info = (const float*)d_in[1];
    const float* fut  = (const float*)d_in[2];
    const float* W1   = (const float*)d_in[3];
    const float* b1   = (const float*)d_in[4];
    const float* W2   = (const float*)d_in[5];
    const float* b2   = (const float*)d_in[6];
    const int*   seg  = (const int*)d_in[7];
    float*       out  = (float*)d_out;

    const int M = in_sizes[7];           // 262144 lanes
    const int blocks = M / 64;           // 4096 two-wave blocks, 64 rows each

    lane_attn_kernel<<<blocks, 128, 0, stream>>>(ht, info, fut, W1, b1, W2, b2,
                                                 seg, out);
}